// Round 3
// baseline (1183.568 us; speedup 1.0000x reference)
//
#include <hip/hip_runtime.h>
#include <stdint.h>

typedef unsigned short u16;
typedef __bf16 bf16x8 __attribute__((ext_vector_type(8)));
typedef float f32x4 __attribute__((ext_vector_type(4)));
typedef float f32x16 __attribute__((ext_vector_type(16)));

__device__ __forceinline__ u16 f2b(float f) {
  union { float f; unsigned u; } v; v.f = f;
  unsigned r = v.u + 0x7fffu + ((v.u >> 16) & 1u);
  return (u16)(r >> 16);
}
__device__ __forceinline__ float b2f(u16 b) {
  union { unsigned u; float f; } v; v.u = ((unsigned)b) << 16;
  return v.f;
}

// ---------------------------------------------------------------- cast fp32 -> bf16
__global__ __launch_bounds__(256) void cast_bf16(const float* __restrict__ in,
                                                 u16* __restrict__ out, int n4) {
  int i = blockIdx.x * 256 + threadIdx.x;
  if (i >= n4) return;
  float4 f = ((const float4*)in)[i];
  ushort4 r = make_ushort4(f2b(f.x), f2b(f.y), f2b(f.z), f2b(f.w));
  ((ushort4*)out)[i] = r;
}

// ---------------------------------------------------------------- fold fm weight into projection
// out[h*128+j, i] = sum_d fmw[j,d] * W[h*128+d, i]   (bf16 out)
__global__ __launch_bounds__(256) void fold_w(const float* __restrict__ W,
                                              const float* __restrict__ fmw,
                                              u16* __restrict__ out) {
  int hj = blockIdx.x;
  int h = hj >> 7, j = hj & 127;
  int i0 = threadIdx.x * 4;
  float a0 = 0.f, a1 = 0.f, a2 = 0.f, a3 = 0.f;
  const float* Wh = W + (size_t)(h * 128) * 1024 + i0;
  const float* fw = fmw + j * 128;
  for (int d = 0; d < 128; ++d) {
    float wv = fw[d];
    const float* wr = Wh + (size_t)d * 1024;
    a0 += wv * wr[0]; a1 += wv * wr[1]; a2 += wv * wr[2]; a3 += wv * wr[3];
  }
  ushort4 r = make_ushort4(f2b(a0), f2b(a1), f2b(a2), f2b(a3));
  ((ushort4*)(out + (size_t)hj * 1024))[threadIdx.x] = r;
}

// ---------------------------------------------------------------- BT GEMM (plain LDS staging)
// C[M,N] = A[M,K] @ B[N,K]^T, A/B bf16, OUT_BF16 ? bf16 : fp32 output
template <int OUT_BF16>
__global__ __launch_bounds__(256) void gemm_bt(const u16* __restrict__ A,
                                               const u16* __restrict__ B,
                                               void* __restrict__ Cv,
                                               int M, int N, int K) {
  __shared__ u16 As[128 * 64];
  __shared__ u16 Bs[128 * 64];
  const int tid = threadIdx.x;
  const int m0 = blockIdx.y * 128, n0 = blockIdx.x * 128;
  const int wave = tid >> 6, lane = tid & 63;
  const int wm = (wave >> 1) << 6, wn = (wave & 1) << 6;
  f32x4 acc[4][4] = {};
  const int srow = tid >> 3;         // 0..31
  const int scol = (tid & 7) << 3;   // 0..56
  const u16* Ab = A + (size_t)(m0 + srow) * K + scol;
  const u16* Bb = B + (size_t)(n0 + srow) * K + scol;
  u16* Asp = As + srow * 64 + scol;
  u16* Bsp = Bs + srow * 64 + scol;
  const int fm = lane & 15;
  const int fk = (lane >> 4) << 3;
  for (int kt = 0; kt < K; kt += 64) {
    uint4 av[4], bv[4];
#pragma unroll
    for (int i = 0; i < 4; ++i) {
      av[i] = *(const uint4*)(Ab + (size_t)i * 32 * K + kt);
      bv[i] = *(const uint4*)(Bb + (size_t)i * 32 * K + kt);
    }
    __syncthreads();  // previous tile's readers done
#pragma unroll
    for (int i = 0; i < 4; ++i) {
      *(uint4*)(Asp + i * 32 * 64) = av[i];
      *(uint4*)(Bsp + i * 32 * 64) = bv[i];
    }
    __syncthreads();
#pragma unroll
    for (int kb = 0; kb < 2; ++kb) {
      bf16x8 af[4], bfr[4];
#pragma unroll
      for (int i = 0; i < 4; ++i)
        af[i] = *(const bf16x8*)(As + (wm + i * 16 + fm) * 64 + kb * 32 + fk);
#pragma unroll
      for (int j = 0; j < 4; ++j)
        bfr[j] = *(const bf16x8*)(Bs + (wn + j * 16 + fm) * 64 + kb * 32 + fk);
#pragma unroll
      for (int i = 0; i < 4; ++i)
#pragma unroll
        for (int j = 0; j < 4; ++j)
          acc[i][j] = __builtin_amdgcn_mfma_f32_16x16x32_bf16(af[i], bfr[j], acc[i][j], 0, 0, 0);
    }
  }
  const int cr = (lane >> 4) << 2;
  const int cc = lane & 15;
#pragma unroll
  for (int i = 0; i < 4; ++i)
#pragma unroll
    for (int r = 0; r < 4; ++r) {
      size_t row = (size_t)(m0 + wm + i * 16 + cr + r);
#pragma unroll
      for (int j = 0; j < 4; ++j) {
        float v = acc[i][j][r];
        size_t col = (size_t)(n0 + wn + j * 16 + cc);
        if (OUT_BF16)
          ((u16*)Cv)[row * N + col] = f2b(v);
        else
          ((float*)Cv)[row * N + col] = v;
      }
    }
}

// ---------------------------------------------------------------- hedgehog softmax
// y: [nrows rowheads][128] bf16; phi: [nrows][256] bf16
__global__ __launch_bounds__(256) void hedgehog_sm(const u16* __restrict__ y,
                                                   const float* __restrict__ bias,
                                                   u16* __restrict__ phi, float scale) {
  int wave = threadIdx.x >> 6, lane = threadIdx.x & 63;
  int rh = blockIdx.x * 4 + wave;
  const u16* yr = y + (size_t)rh * 128;
  float a1 = 2.f * (b2f(yr[lane]) + bias[lane]);
  float a2 = 2.f * (b2f(yr[lane + 64]) + bias[lane + 64]);
  float mx = fmaxf(fabsf(a1), fabsf(a2));
#pragma unroll
  for (int off = 32; off; off >>= 1) mx = fmaxf(mx, __shfl_xor(mx, off, 64));
  float e1 = __expf(a1 - mx), e2 = __expf(a2 - mx);
  float n1 = __expf(-a1 - mx), n2 = __expf(-a2 - mx);
  float s = e1 + e2 + n1 + n2;
#pragma unroll
  for (int off = 32; off; off >>= 1) s += __shfl_xor(s, off, 64);
  float inv = scale / s;
  u16* pr = phi + (size_t)rh * 256;
  pr[lane] = f2b(e1 * inv);
  pr[lane + 64] = f2b(e2 * inv);
  pr[lane + 128] = f2b(n1 * inv);
  pr[lane + 192] = f2b(n2 * inv);
}

// ---------------------------------------------------------------- attention phase A (one batch)
// per chunk: intra attn -> o_intra (write), KV = k^T v stored [vc][d] bf16.
__global__ __launch_bounds__(256, 1) void attn_intra_kv(const u16* __restrict__ phi_q,
                                                        const u16* __restrict__ phi_k,
                                                        const u16* __restrict__ vb,
                                                        float* __restrict__ o,
                                                        u16* __restrict__ kv) {
  __shared__ u16 lds[32256];
  u16* Kt = lds;               // [256][72]  k transposed [d][t']
  u16* Vt = Kt + 256 * 72;     // [128][72]  v transposed [vc][t']
  u16* At = Vt + 128 * 72;     // [64][72]   masked attn bf16
  int g = blockIdx.x;          // 0..1023: h = g>>7, n = g&127
  int n = g & 127, h = g >> 7;
  size_t rowbase = ((size_t)(n * 64) * 8 + h);
  const u16* qg = phi_q + rowbase * 256;
  const u16* kg = phi_k + rowbase * 256;
  const u16* vg = vb + rowbase * 128;
  int tid = threadIdx.x, lane = tid & 63, w = tid >> 6;

  { // stage K transposed
    int r4 = (tid & 15) << 2;   // t'0
    int d0 = (tid >> 4) << 4;   // 0..240
    u16 tmp[4][16];
#pragma unroll
    for (int r = 0; r < 4; ++r) {
      const u16* src = kg + (size_t)(r4 + r) * 2048 + d0;
      *(uint4*)(tmp[r]) = *(const uint4*)(src);
      *(uint4*)(tmp[r] + 8) = *(const uint4*)(src + 8);
    }
#pragma unroll
    for (int j = 0; j < 16; ++j) {
      ushort4 pk = make_ushort4(tmp[0][j], tmp[1][j], tmp[2][j], tmp[3][j]);
      *(ushort4*)(Kt + (d0 + j) * 72 + r4) = pk;
    }
  }
  { // stage V transposed
    int r4 = (tid & 15) << 2;
    int vc0 = (tid >> 4) << 3;
    u16 tmp[4][8];
#pragma unroll
    for (int r = 0; r < 4; ++r)
      *(uint4*)(tmp[r]) = *(const uint4*)(vg + (size_t)(r4 + r) * 1024 + vc0);
#pragma unroll
    for (int j = 0; j < 8; ++j) {
      ushort4 pk = make_ushort4(tmp[0][j], tmp[1][j], tmp[2][j], tmp[3][j]);
      *(ushort4*)(Vt + (vc0 + j) * 72 + r4) = pk;
    }
  }

  const int fr = lane & 31;
  const int fg = (lane >> 5) << 3;
  const int mw = (w >> 1) << 5;   // t base
  const int nw = (w & 1) << 5;    // t' base
  // attn = q @ k^T  (32x32 tile per wave), A/B fragments from global
  f32x16 accA = {};
#pragma unroll
  for (int ks = 0; ks < 16; ++ks) {
    bf16x8 a = *(const bf16x8*)(qg + (size_t)(mw + fr) * 2048 + ks * 16 + fg);
    bf16x8 bb = *(const bf16x8*)(kg + (size_t)(nw + fr) * 2048 + ks * 16 + fg);
    accA = __builtin_amdgcn_mfma_f32_32x32x16_bf16(a, bb, accA, 0, 0, 0);
  }
  __syncthreads();  // Kt/Vt staging complete
  { // mask (causal incl diagonal) + write bf16 to At
    int col = nw + (lane & 31);
    int rbase = (lane >> 5) << 2;
#pragma unroll
    for (int r = 0; r < 16; ++r) {
      int row = mw + (r & 3) + ((r >> 2) << 3) + rbase;
      float val = (col <= row) ? accA[r] : 0.f;
      At[row * 72 + col] = f2b(val);
    }
  }
  __syncthreads();

  // o_intra = attn @ v : wave -> t-tile (w>>1), vc range (w&1)*64..+64
  const int no = (w & 1) << 6;
  f32x16 accO[2] = {};
#pragma unroll
  for (int ks = 0; ks < 4; ++ks) {
    bf16x8 a = *(const bf16x8*)(At + (mw + fr) * 72 + ks * 16 + fg);
#pragma unroll
    for (int j = 0; j < 2; ++j) {
      bf16x8 bb = *(const bf16x8*)(Vt + (no + j * 32 + fr) * 72 + ks * 16 + fg);
      accO[j] = __builtin_amdgcn_mfma_f32_32x32x16_bf16(a, bb, accO[j], 0, 0, 0);
    }
  }
  {
    float* og = o + rowbase * 128;
    int rbase = (lane >> 5) << 2;
#pragma unroll
    for (int j = 0; j < 2; ++j)
#pragma unroll
      for (int r = 0; r < 16; ++r) {
        int row = mw + (r & 3) + ((r >> 2) << 3) + rbase;
        int vc = no + j * 32 + (lane & 31);
        og[(size_t)row * 1024 + vc] = accO[j][r];
      }
  }

  // KV[vc][d] = sum_t' v[t'][vc] k[t'][d] : A=Vt, B=Kt; wave w covers d in [w*64, w*64+64)
  f32x16 accKV[8] = {};
  const int nd = w << 6;
#pragma unroll
  for (int ks = 0; ks < 4; ++ks) {
    bf16x8 av[4];
#pragma unroll
    for (int mt = 0; mt < 4; ++mt)
      av[mt] = *(const bf16x8*)(Vt + (mt * 32 + fr) * 72 + ks * 16 + fg);
#pragma unroll
    for (int nt = 0; nt < 2; ++nt) {
      bf16x8 bk = *(const bf16x8*)(Kt + (nd + nt * 32 + fr) * 72 + ks * 16 + fg);
#pragma unroll
      for (int mt = 0; mt < 4; ++mt)
        accKV[mt * 2 + nt] =
            __builtin_amdgcn_mfma_f32_32x32x16_bf16(av[mt], bk, accKV[mt * 2 + nt], 0, 0, 0);
    }
  }
  {
    u16* kvg = kv + (size_t)g * 32768;
    int rbase = (lane >> 5) << 2;
#pragma unroll
    for (int mt = 0; mt < 4; ++mt)
#pragma unroll
      for (int nt = 0; nt < 2; ++nt) {
        f32x16 acc = accKV[mt * 2 + nt];
#pragma unroll
        for (int r = 0; r < 16; ++r) {
          int vc = mt * 32 + (r & 3) + ((r >> 2) << 3) + rbase;
          int d = nd + nt * 32 + (lane & 31);
          kvg[(size_t)vc * 256 + d] = f2b(acc[r]);
        }
      }
  }
}

// ---------------------------------------------------------------- attention phase B (one batch)
// in-place exclusive prefix over 128 chunks per h; 8 bf16 per thread; fp32 running sum
__global__ __launch_bounds__(64) void kv_scan(u16* __restrict__ kv) {
  int idx = blockIdx.x * 64 + threadIdx.x;  // 0..32767
  int h = idx >> 12;                        // 0..7
  int e8 = idx & 4095;
  u16* p = kv + (size_t)h * 128 * 32768 + (size_t)e8 * 8;
  float run[8] = {};
  for (int n = 0; n < 128; ++n) {
    uint4 raw = *(const uint4*)p;
    u16* rv = (u16*)&raw;
    uint4 outw;
    u16* ov = (u16*)&outw;
#pragma unroll
    for (int i = 0; i < 8; ++i) {
      float v = b2f(rv[i]);
      ov[i] = f2b(run[i]);
      run[i] += v;
    }
    *(uint4*)p = outw;
    p += 32768;
  }
}

// ---------------------------------------------------------------- attention phase C (one batch)
// o += q @ S  (S = exclusive prefix KV, layout [vc][d]); zero LDS
__global__ __launch_bounds__(256, 1) void attn_inter(const u16* __restrict__ phi_q,
                                                     const u16* __restrict__ kv,
                                                     float* __restrict__ o) {
  int g = blockIdx.x;
  int n = g & 127, h = g >> 7;
  size_t rowbase = ((size_t)(n * 64) * 8 + h);
  const u16* qg = phi_q + rowbase * 256;
  const u16* sg = kv + (size_t)g * 32768;
  int tid = threadIdx.x, lane = tid & 63, w = tid >> 6;
  const int mw = (w >> 1) << 5;  // t
  const int nv = (w & 1) << 6;   // vc
  const int fr = lane & 31, fg = (lane >> 5) << 3;
  f32x16 acc[2] = {};
#pragma unroll
  for (int ks = 0; ks < 16; ++ks) {
    bf16x8 a = *(const bf16x8*)(qg + (size_t)(mw + fr) * 2048 + ks * 16 + fg);
#pragma unroll
    for (int j = 0; j < 2; ++j) {
      bf16x8 bb = *(const bf16x8*)(sg + (size_t)(nv + j * 32 + fr) * 256 + ks * 16 + fg);
      acc[j] = __builtin_amdgcn_mfma_f32_32x32x16_bf16(a, bb, acc[j], 0, 0, 0);
    }
  }
  float* og = o + rowbase * 128;
  int rbase = (lane >> 5) << 2;
#pragma unroll
  for (int j = 0; j < 2; ++j)
#pragma unroll
    for (int r = 0; r < 16; ++r) {
      int row = mw + (r & 3) + ((r >> 2) << 3) + rbase;
      int vc = nv + j * 32 + (lane & 31);
      og[(size_t)row * 1024 + vc] += acc[j][r];
    }
}

// ---------------------------------------------------------------- rmsnorm (per 1024-dim row)
__global__ __launch_bounds__(256) void rmsnorm_k(const float* __restrict__ o,
                                                 u16* __restrict__ on) {
  __shared__ float red[4];
  int row = blockIdx.x;
  const float* orow = o + (size_t)row * 1024;
  int tid = threadIdx.x;
  float4 v = ((const float4*)orow)[tid];
  float ss = v.x * v.x + v.y * v.y + v.z * v.z + v.w * v.w;
#pragma unroll
  for (int off = 32; off; off >>= 1) ss += __shfl_xor(ss, off, 64);
  if ((tid & 63) == 0) red[tid >> 6] = ss;
  __syncthreads();
  float tot = red[0] + red[1] + red[2] + red[3];
  float rms = rsqrtf(tot * (1.f / 1024.f) + 1e-5f);
  ushort4 r = make_ushort4(f2b(v.x * rms), f2b(v.y * rms), f2b(v.z * rms), f2b(v.w * rms));
  ((ushort4*)(on + (size_t)row * 1024))[tid] = r;
}

// ---------------------------------------------------------------- launch
extern "C" void kernel_launch(void* const* d_in, const int* in_sizes, int n_in,
                              void* d_out, int out_size, void* d_ws, size_t ws_size,
                              hipStream_t stream) {
  const float* x     = (const float*)d_in[0];
  const float* Wq    = (const float*)d_in[1];
  const float* Wk    = (const float*)d_in[2];
  const float* Wv    = (const float*)d_in[3];
  const float* Wo    = (const float*)d_in[4];
  const float* fmq_w = (const float*)d_in[5];
  const float* fmq_b = (const float*)d_in[6];
  const float* fmk_w = (const float*)d_in[7];
  const float* fmk_b = (const float*)d_in[8];

  // Per-batch workspace layout (batches processed sequentially; 184 MiB total).
  // kv region [0,64 MiB) also hosts xb/yb/onb (dead while kv is live).
  char* ws = (char*)d_ws;
  u16*   kvb  = (u16*)(ws + 0);            // 64 MiB
  u16*   xb   = (u16*)(ws + 0);            // 16 MiB
  u16*   yb   = (u16*)(ws + 16777216);     // 16 MiB
  u16*   onb  = (u16*)(ws + 33554432);     // 16 MiB
  u16*   phiq = (u16*)(ws + 67108864);     // 32 MiB
  u16*   phik = (u16*)(ws + 100663296);    // 32 MiB
  u16*   vbuf = (u16*)(ws + 134217728);    // 16 MiB
  float* obuf = (float*)(ws + 150994944);  // 32 MiB
  u16*   wqc  = (u16*)(ws + 184549376);    // 2 MiB
  u16*   wkc  = (u16*)(ws + 186646528);    // 2 MiB
  u16*   wvb  = (u16*)(ws + 188743680);    // 2 MiB
  u16*   wob  = (u16*)(ws + 190840832);    // 2 MiB -> end 192937984 (184 MiB)

  // weight prep (once)
  cast_bf16<<<1024, 256, 0, stream>>>(Wv, wvb, 262144);
  cast_bf16<<<1024, 256, 0, stream>>>(Wo, wob, 262144);
  fold_w<<<1024, 256, 0, stream>>>(Wq, fmq_w, wqc);
  fold_w<<<1024, 256, 0, stream>>>(Wk, fmk_w, wkc);

  dim3 ggrid(8, 64);
  for (int b = 0; b < 2; ++b) {
    const float* xsrc = x + (size_t)b * 8388608;
    float* osrc = (float*)d_out + (size_t)b * 8388608;
    cast_bf16<<<8192, 256, 0, stream>>>(xsrc, xb, 2097152);
    gemm_bt<1><<<ggrid, 256, 0, stream>>>(xb, wqc, yb, 8192, 1024, 1024);
    hedgehog_sm<<<16384, 256, 0, stream>>>(yb, fmq_b, phiq, 0.0625f);  // 256^-0.5
    gemm_bt<1><<<ggrid, 256, 0, stream>>>(xb, wkc, yb, 8192, 1024, 1024);
    hedgehog_sm<<<16384, 256, 0, stream>>>(yb, fmk_b, phik, 1.0f);
    gemm_bt<1><<<ggrid, 256, 0, stream>>>(xb, wvb, vbuf, 8192, 1024, 1024);
    attn_intra_kv<<<1024, 256, 0, stream>>>(phiq, phik, vbuf, obuf, kvb);
    kv_scan<<<512, 64, 0, stream>>>(kvb);
    attn_inter<<<1024, 256, 0, stream>>>(phiq, kvb, obuf);
    rmsnorm_k<<<8192, 256, 0, stream>>>(obuf, onb);
    gemm_bt<0><<<ggrid, 256, 0, stream>>>(onb, wob, osrc, 8192, 1024, 1024);
  }
}

// Round 4
// 722.808 us; speedup vs baseline: 1.6375x; 1.6375x over previous
//
#include <hip/hip_runtime.h>
#include <stdint.h>

typedef unsigned short u16;
typedef __bf16 bf16x8 __attribute__((ext_vector_type(8)));
typedef float f32x4 __attribute__((ext_vector_type(4)));
typedef float f32x16 __attribute__((ext_vector_type(16)));

__device__ __forceinline__ u16 f2b(float f) {
  union { float f; unsigned u; } v; v.f = f;
  unsigned r = v.u + 0x7fffu + ((v.u >> 16) & 1u);
  return (u16)(r >> 16);
}
__device__ __forceinline__ float b2f(u16 b) {
  union { unsigned u; float f; } v; v.u = ((unsigned)b) << 16;
  return v.f;
}

// ---------------------------------------------------------------- cast fp32 -> bf16
__global__ __launch_bounds__(256) void cast_bf16(const float* __restrict__ in,
                                                 u16* __restrict__ out, int n4) {
  int i = blockIdx.x * 256 + threadIdx.x;
  if (i >= n4) return;
  float4 f = ((const float4*)in)[i];
  ushort4 r = make_ushort4(f2b(f.x), f2b(f.y), f2b(f.z), f2b(f.w));
  ((ushort4*)out)[i] = r;
}

// ---------------------------------------------------------------- fold fm weight into projection
// out[h*128+j, i] = sum_d fmw[j,d] * W[h*128+d, i]   (bf16 out)
__global__ __launch_bounds__(256) void fold_w(const float* __restrict__ W,
                                              const float* __restrict__ fmw,
                                              u16* __restrict__ out) {
  int hj = blockIdx.x;
  int h = hj >> 7, j = hj & 127;
  int i0 = threadIdx.x * 4;
  float a0 = 0.f, a1 = 0.f, a2 = 0.f, a3 = 0.f;
  const float* Wh = W + (size_t)(h * 128) * 1024 + i0;
  const float* fw = fmw + j * 128;
  for (int d = 0; d < 128; ++d) {
    float wv = fw[d];
    const float* wr = Wh + (size_t)d * 1024;
    a0 += wv * wr[0]; a1 += wv * wr[1]; a2 += wv * wr[2]; a3 += wv * wr[3];
  }
  ushort4 r = make_ushort4(f2b(a0), f2b(a1), f2b(a2), f2b(a3));
  ((ushort4*)(out + (size_t)hj * 1024))[threadIdx.x] = r;
}

// ---------------------------------------------------------------- m97-style BT GEMM
// C[M,N] = A[M,K] @ B[N,K]^T, A/B bf16, OUT_BF16 ? bf16 : fp32 output.
// global_load_lds staging (no VGPR round-trip -> no spill), XCD-sliced m-tiles,
// LDS-staged fully-coalesced epilogue.
template <int OUT_BF16>
__global__ __launch_bounds__(256) void gemm_bt(const u16* __restrict__ A,
                                               const u16* __restrict__ B,
                                               void* __restrict__ Cv,
                                               int M, int N, int K) {
  __shared__ u16 smem[16384];  // As[128*64] | Bs[128*64]; reused as C tile
  u16* As = smem;
  u16* Bs = smem + 8192;
  const int tid = threadIdx.x;
  // XCD swizzle: gridDim.x == 8 (n-tiles), gridDim.y % 8 == 0 (m-tiles).
  // Blocks sharing an A row-tile land on the same XCD (round-robin dispatch).
  int g = blockIdx.y * gridDim.x + blockIdx.x;
  int xcd = g & 7;
  int local = g >> 3;
  int mt = xcd * (gridDim.y >> 3) + (local >> 3);
  int nt = local & 7;
  const int m0 = mt * 128, n0 = nt * 128;
  const int wave = tid >> 6, lane = tid & 63;
  const int wm = (wave >> 1) << 6, wn = (wave & 1) << 6;
  f32x4 acc[4][4] = {};
  const int srow = tid >> 3;         // 0..31
  const int scol = (tid & 7) << 3;   // 0..56
  const u16* Ab = A + (size_t)(m0 + srow) * K + scol;
  const u16* Bb = B + (size_t)(n0 + srow) * K + scol;
  u16* Asp = As + srow * 64 + scol;
  u16* Bsp = Bs + srow * 64 + scol;
  const int fm = lane & 15;
  const int fk = (lane >> 4) << 3;
  for (int kt = 0; kt < K; kt += 64) {
#pragma unroll
    for (int i = 0; i < 4; ++i) {
      __builtin_amdgcn_global_load_lds(
          (__attribute__((address_space(1))) unsigned int*)(Ab + (size_t)i * 32 * K + kt),
          (__attribute__((address_space(3))) unsigned int*)(Asp + i * 32 * 64), 16, 0, 0);
      __builtin_amdgcn_global_load_lds(
          (__attribute__((address_space(1))) unsigned int*)(Bb + (size_t)i * 32 * K + kt),
          (__attribute__((address_space(3))) unsigned int*)(Bsp + i * 32 * 64), 16, 0, 0);
    }
    __syncthreads();
#pragma unroll
    for (int kb = 0; kb < 2; ++kb) {
      bf16x8 af[4], bfr[4];
#pragma unroll
      for (int i = 0; i < 4; ++i)
        af[i] = *(const bf16x8*)(As + (wm + i * 16 + fm) * 64 + kb * 32 + fk);
#pragma unroll
      for (int j = 0; j < 4; ++j)
        bfr[j] = *(const bf16x8*)(Bs + (wn + j * 16 + fm) * 64 + kb * 32 + fk);
#pragma unroll
      for (int i = 0; i < 4; ++i)
#pragma unroll
        for (int j = 0; j < 4; ++j)
          acc[i][j] = __builtin_amdgcn_mfma_f32_16x16x32_bf16(af[i], bfr[j], acc[i][j], 0, 0, 0);
    }
    __syncthreads();
  }
  const int cr = (lane >> 4) << 2;
  const int cc = lane & 15;
  if (OUT_BF16) {
    u16* Cs = smem;  // 128x128 u16 = 32 KiB
#pragma unroll
    for (int i = 0; i < 4; ++i)
#pragma unroll
      for (int j = 0; j < 4; ++j)
#pragma unroll
        for (int r = 0; r < 4; ++r)
          Cs[(wm + i * 16 + cr + r) * 128 + wn + j * 16 + cc] = f2b(acc[i][j][r]);
    __syncthreads();
    u16* Cg = (u16*)Cv;
#pragma unroll
    for (int i = 0; i < 8; ++i) {
      int row = (i >> 1) * 32 + (tid >> 3);
      int col = ((i & 1) * 8 + (tid & 7)) * 8;
      *(uint4*)(Cg + (size_t)(m0 + row) * N + n0 + col) = *(const uint4*)(Cs + row * 128 + col);
    }
  } else {
    float* Csf = (float*)smem;  // 64x128 f32 = 32 KiB (two half-passes)
    float* Cg = (float*)Cv;
#pragma unroll
    for (int h = 0; h < 2; ++h) {
      __syncthreads();
      if ((wm >> 6) == h) {
#pragma unroll
        for (int i = 0; i < 4; ++i)
#pragma unroll
          for (int j = 0; j < 4; ++j)
#pragma unroll
            for (int r = 0; r < 4; ++r)
              Csf[(i * 16 + cr + r) * 128 + wn + j * 16 + cc] = acc[i][j][r];
      }
      __syncthreads();
#pragma unroll
      for (int i = 0; i < 8; ++i) {
        int row = (i >> 1) * 16 + (tid >> 4);
        int col = ((i & 1) * 16 + (tid & 15)) * 4;
        *(float4*)(Cg + (size_t)(m0 + h * 64 + row) * N + n0 + col) =
            *(const float4*)(Csf + row * 128 + col);
      }
    }
  }
}

// ---------------------------------------------------------------- hedgehog softmax
// y: [nrows rowheads][128] bf16; phi: [nrows][256] bf16
__global__ __launch_bounds__(256) void hedgehog_sm(const u16* __restrict__ y,
                                                   const float* __restrict__ bias,
                                                   u16* __restrict__ phi, float scale) {
  int wave = threadIdx.x >> 6, lane = threadIdx.x & 63;
  int rh = blockIdx.x * 4 + wave;
  const u16* yr = y + (size_t)rh * 128;
  float a1 = 2.f * (b2f(yr[lane]) + bias[lane]);
  float a2 = 2.f * (b2f(yr[lane + 64]) + bias[lane + 64]);
  float mx = fmaxf(fabsf(a1), fabsf(a2));
#pragma unroll
  for (int off = 32; off; off >>= 1) mx = fmaxf(mx, __shfl_xor(mx, off, 64));
  float e1 = __expf(a1 - mx), e2 = __expf(a2 - mx);
  float n1 = __expf(-a1 - mx), n2 = __expf(-a2 - mx);
  float s = e1 + e2 + n1 + n2;
#pragma unroll
  for (int off = 32; off; off >>= 1) s += __shfl_xor(s, off, 64);
  float inv = scale / s;
  u16* pr = phi + (size_t)rh * 256;
  pr[lane] = f2b(e1 * inv);
  pr[lane + 64] = f2b(e2 * inv);
  pr[lane + 128] = f2b(n1 * inv);
  pr[lane + 192] = f2b(n2 * inv);
}

// ---------------------------------------------------------------- attention phase A (one batch)
// per chunk: intra attn -> o_intra (write), KV = k^T v stored [vc][d] bf16.
__global__ __launch_bounds__(256, 1) void attn_intra_kv(const u16* __restrict__ phi_q,
                                                        const u16* __restrict__ phi_k,
                                                        const u16* __restrict__ vb,
                                                        float* __restrict__ o,
                                                        u16* __restrict__ kv) {
  __shared__ u16 lds[32256];
  u16* Kt = lds;               // [256][72]  k transposed [d][t']
  u16* Vt = Kt + 256 * 72;     // [128][72]  v transposed [vc][t']
  u16* At = Vt + 128 * 72;     // [64][72]   masked attn bf16
  int g = blockIdx.x;          // 0..1023: h = g>>7, n = g&127
  int n = g & 127, h = g >> 7;
  size_t rowbase = ((size_t)(n * 64) * 8 + h);
  const u16* qg = phi_q + rowbase * 256;
  const u16* kg = phi_k + rowbase * 256;
  const u16* vg = vb + rowbase * 128;
  int tid = threadIdx.x, lane = tid & 63, w = tid >> 6;

  { // stage K transposed
    int r4 = (tid & 15) << 2;   // t'0
    int d0 = (tid >> 4) << 4;   // 0..240
    u16 tmp[4][16];
#pragma unroll
    for (int r = 0; r < 4; ++r) {
      const u16* src = kg + (size_t)(r4 + r) * 2048 + d0;
      *(uint4*)(tmp[r]) = *(const uint4*)(src);
      *(uint4*)(tmp[r] + 8) = *(const uint4*)(src + 8);
    }
#pragma unroll
    for (int j = 0; j < 16; ++j) {
      ushort4 pk = make_ushort4(tmp[0][j], tmp[1][j], tmp[2][j], tmp[3][j]);
      *(ushort4*)(Kt + (d0 + j) * 72 + r4) = pk;
    }
  }
  { // stage V transposed
    int r4 = (tid & 15) << 2;
    int vc0 = (tid >> 4) << 3;
    u16 tmp[4][8];
#pragma unroll
    for (int r = 0; r < 4; ++r)
      *(uint4*)(tmp[r]) = *(const uint4*)(vg + (size_t)(r4 + r) * 1024 + vc0);
#pragma unroll
    for (int j = 0; j < 8; ++j) {
      ushort4 pk = make_ushort4(tmp[0][j], tmp[1][j], tmp[2][j], tmp[3][j]);
      *(ushort4*)(Vt + (vc0 + j) * 72 + r4) = pk;
    }
  }

  const int fr = lane & 31;
  const int fg = (lane >> 5) << 3;
  const int mw = (w >> 1) << 5;   // t base
  const int nw = (w & 1) << 5;    // t' base
  // attn = q @ k^T  (32x32 tile per wave), A/B fragments from global
  f32x16 accA = {};
#pragma unroll
  for (int ks = 0; ks < 16; ++ks) {
    bf16x8 a = *(const bf16x8*)(qg + (size_t)(mw + fr) * 2048 + ks * 16 + fg);
    bf16x8 bb = *(const bf16x8*)(kg + (size_t)(nw + fr) * 2048 + ks * 16 + fg);
    accA = __builtin_amdgcn_mfma_f32_32x32x16_bf16(a, bb, accA, 0, 0, 0);
  }
  __syncthreads();  // Kt/Vt staging complete
  { // mask (causal incl diagonal) + write bf16 to At
    int col = nw + (lane & 31);
    int rbase = (lane >> 5) << 2;
#pragma unroll
    for (int r = 0; r < 16; ++r) {
      int row = mw + (r & 3) + ((r >> 2) << 3) + rbase;
      float val = (col <= row) ? accA[r] : 0.f;
      At[row * 72 + col] = f2b(val);
    }
  }
  __syncthreads();

  // o_intra = attn @ v : wave -> t-tile (w>>1), vc range (w&1)*64..+64
  const int no = (w & 1) << 6;
  f32x16 accO[2] = {};
#pragma unroll
  for (int ks = 0; ks < 4; ++ks) {
    bf16x8 a = *(const bf16x8*)(At + (mw + fr) * 72 + ks * 16 + fg);
#pragma unroll
    for (int j = 0; j < 2; ++j) {
      bf16x8 bb = *(const bf16x8*)(Vt + (no + j * 32 + fr) * 72 + ks * 16 + fg);
      accO[j] = __builtin_amdgcn_mfma_f32_32x32x16_bf16(a, bb, accO[j], 0, 0, 0);
    }
  }
  {
    float* og = o + rowbase * 128;
    int rbase = (lane >> 5) << 2;
#pragma unroll
    for (int j = 0; j < 2; ++j)
#pragma unroll
      for (int r = 0; r < 16; ++r) {
        int row = mw + (r & 3) + ((r >> 2) << 3) + rbase;
        int vc = no + j * 32 + (lane & 31);
        og[(size_t)row * 1024 + vc] = accO[j][r];
      }
  }

  // KV[vc][d] = sum_t' v[t'][vc] k[t'][d] : A=Vt, B=Kt; wave w covers d in [w*64, w*64+64)
  f32x16 accKV[8] = {};
  const int nd = w << 6;
#pragma unroll
  for (int ks = 0; ks < 4; ++ks) {
    bf16x8 av[4];
#pragma unroll
    for (int mt = 0; mt < 4; ++mt)
      av[mt] = *(const bf16x8*)(Vt + (mt * 32 + fr) * 72 + ks * 16 + fg);
#pragma unroll
    for (int nt = 0; nt < 2; ++nt) {
      bf16x8 bk = *(const bf16x8*)(Kt + (nd + nt * 32 + fr) * 72 + ks * 16 + fg);
#pragma unroll
      for (int mt = 0; mt < 4; ++mt)
        accKV[mt * 2 + nt] =
            __builtin_amdgcn_mfma_f32_32x32x16_bf16(av[mt], bk, accKV[mt * 2 + nt], 0, 0, 0);
    }
  }
  {
    u16* kvg = kv + (size_t)g * 32768;
    int rbase = (lane >> 5) << 2;
#pragma unroll
    for (int mt = 0; mt < 4; ++mt)
#pragma unroll
      for (int nt = 0; nt < 2; ++nt) {
        f32x16 acc = accKV[mt * 2 + nt];
#pragma unroll
        for (int r = 0; r < 16; ++r) {
          int vc = mt * 32 + (r & 3) + ((r >> 2) << 3) + rbase;
          int d = nd + nt * 32 + (lane & 31);
          kvg[(size_t)vc * 256 + d] = f2b(acc[r]);
        }
      }
  }
}

// ---------------------------------------------------------------- attention phase B (one batch)
// in-place exclusive prefix over 128 chunks per h; 8 bf16 per thread; fp32 running sum
__global__ __launch_bounds__(64) void kv_scan(u16* __restrict__ kv) {
  int idx = blockIdx.x * 64 + threadIdx.x;  // 0..32767
  int h = idx >> 12;                        // 0..7
  int e8 = idx & 4095;
  u16* p = kv + (size_t)h * 128 * 32768 + (size_t)e8 * 8;
  float run[8] = {};
  for (int n = 0; n < 128; ++n) {
    uint4 raw = *(const uint4*)p;
    u16* rv = (u16*)&raw;
    uint4 outw;
    u16* ov = (u16*)&outw;
#pragma unroll
    for (int i = 0; i < 8; ++i) {
      float v = b2f(rv[i]);
      ov[i] = f2b(run[i]);
      run[i] += v;
    }
    *(uint4*)p = outw;
    p += 32768;
  }
}

// ---------------------------------------------------------------- attention phase C (one batch)
// o += q @ S  (S = exclusive prefix KV, layout [vc][d]); zero LDS
__global__ __launch_bounds__(256, 1) void attn_inter(const u16* __restrict__ phi_q,
                                                     const u16* __restrict__ kv,
                                                     float* __restrict__ o) {
  int g = blockIdx.x;
  int n = g & 127, h = g >> 7;
  size_t rowbase = ((size_t)(n * 64) * 8 + h);
  const u16* qg = phi_q + rowbase * 256;
  const u16* sg = kv + (size_t)g * 32768;
  int tid = threadIdx.x, lane = tid & 63, w = tid >> 6;
  const int mw = (w >> 1) << 5;  // t
  const int nv = (w & 1) << 6;   // vc
  const int fr = lane & 31, fg = (lane >> 5) << 3;
  f32x16 acc[2] = {};
#pragma unroll
  for (int ks = 0; ks < 16; ++ks) {
    bf16x8 a = *(const bf16x8*)(qg + (size_t)(mw + fr) * 2048 + ks * 16 + fg);
#pragma unroll
    for (int j = 0; j < 2; ++j) {
      bf16x8 bb = *(const bf16x8*)(sg + (size_t)(nv + j * 32 + fr) * 256 + ks * 16 + fg);
      acc[j] = __builtin_amdgcn_mfma_f32_32x32x16_bf16(a, bb, acc[j], 0, 0, 0);
    }
  }
  float* og = o + rowbase * 128;
  int rbase = (lane >> 5) << 2;
#pragma unroll
  for (int j = 0; j < 2; ++j)
#pragma unroll
    for (int r = 0; r < 16; ++r) {
      int row = mw + (r & 3) + ((r >> 2) << 3) + rbase;
      int vc = nv + j * 32 + (lane & 31);
      og[(size_t)row * 1024 + vc] += acc[j][r];
    }
}

// ---------------------------------------------------------------- rmsnorm (per 1024-dim row)
__global__ __launch_bounds__(256) void rmsnorm_k(const float* __restrict__ o,
                                                 u16* __restrict__ on) {
  __shared__ float red[4];
  int row = blockIdx.x;
  const float* orow = o + (size_t)row * 1024;
  int tid = threadIdx.x;
  float4 v = ((const float4*)orow)[tid];
  float ss = v.x * v.x + v.y * v.y + v.z * v.z + v.w * v.w;
#pragma unroll
  for (int off = 32; off; off >>= 1) ss += __shfl_xor(ss, off, 64);
  if ((tid & 63) == 0) red[tid >> 6] = ss;
  __syncthreads();
  float tot = red[0] + red[1] + red[2] + red[3];
  float rms = rsqrtf(tot * (1.f / 1024.f) + 1e-5f);
  ushort4 r = make_ushort4(f2b(v.x * rms), f2b(v.y * rms), f2b(v.z * rms), f2b(v.w * rms));
  ((ushort4*)(on + (size_t)row * 1024))[tid] = r;
}

// ---------------------------------------------------------------- launch
extern "C" void kernel_launch(void* const* d_in, const int* in_sizes, int n_in,
                              void* d_out, int out_size, void* d_ws, size_t ws_size,
                              hipStream_t stream) {
  const float* x     = (const float*)d_in[0];
  const float* Wq    = (const float*)d_in[1];
  const float* Wk    = (const float*)d_in[2];
  const float* Wv    = (const float*)d_in[3];
  const float* Wo    = (const float*)d_in[4];
  const float* fmq_w = (const float*)d_in[5];
  const float* fmq_b = (const float*)d_in[6];
  const float* fmk_w = (const float*)d_in[7];
  const float* fmk_b = (const float*)d_in[8];

  // Per-batch workspace layout (batches processed sequentially; 184 MiB total,
  // proven safe in round 3 — 360 MiB layout faulted).
  char* ws = (char*)d_ws;
  u16*   kvb  = (u16*)(ws + 0);            // 64 MiB
  u16*   xb   = (u16*)(ws + 0);            // 16 MiB (aliases kv)
  u16*   yb   = (u16*)(ws + 16777216);     // 16 MiB (aliases kv)
  u16*   onb  = (u16*)(ws + 33554432);     // 16 MiB (aliases kv)
  u16*   phiq = (u16*)(ws + 67108864);     // 32 MiB
  u16*   phik = (u16*)(ws + 100663296);    // 32 MiB
  u16*   vbuf = (u16*)(ws + 134217728);    // 16 MiB
  float* obuf = (float*)(ws + 150994944);  // 32 MiB
  u16*   wqc  = (u16*)(ws + 184549376);    // 2 MiB
  u16*   wkc  = (u16*)(ws + 186646528);    // 2 MiB
  u16*   wvb  = (u16*)(ws + 188743680);    // 2 MiB
  u16*   wob  = (u16*)(ws + 190840832);    // 2 MiB -> end 192937984 (184 MiB)

  // weight prep (once)
  cast_bf16<<<1024, 256, 0, stream>>>(Wv, wvb, 262144);
  cast_bf16<<<1024, 256, 0, stream>>>(Wo, wob, 262144);
  fold_w<<<1024, 256, 0, stream>>>(Wq, fmq_w, wqc);
  fold_w<<<1024, 256, 0, stream>>>(Wk, fmk_w, wkc);

  dim3 ggrid(8, 64);
  for (int b = 0; b < 2; ++b) {
    const float* xsrc = x + (size_t)b * 8388608;
    float* osrc = (float*)d_out + (size_t)b * 8388608;
    cast_bf16<<<8192, 256, 0, stream>>>(xsrc, xb, 2097152);
    gemm_bt<1><<<ggrid, 256, 0, stream>>>(xb, wqc, yb, 8192, 1024, 1024);
    hedgehog_sm<<<16384, 256, 0, stream>>>(yb, fmq_b, phiq, 0.0625f);  // 256^-0.5
    gemm_bt<1><<<ggrid, 256, 0, stream>>>(xb, wkc, yb, 8192, 1024, 1024);
    hedgehog_sm<<<16384, 256, 0, stream>>>(yb, fmk_b, phik, 1.0f);
    gemm_bt<1><<<ggrid, 256, 0, stream>>>(xb, wvb, vbuf, 8192, 1024, 1024);
    attn_intra_kv<<<1024, 256, 0, stream>>>(phiq, phik, vbuf, obuf, kvb);
    kv_scan<<<512, 64, 0, stream>>>(kvb);
    attn_inter<<<1024, 256, 0, stream>>>(phiq, kvb, obuf);
    rmsnorm_k<<<8192, 256, 0, stream>>>(obuf, onb);
    gemm_bt<0><<<ggrid, 256, 0, stream>>>(onb, wob, osrc, 8192, 1024, 1024);
  }
}

// Round 5
// 696.943 us; speedup vs baseline: 1.6982x; 1.0371x over previous
//
#include <hip/hip_runtime.h>
#include <stdint.h>

typedef unsigned short u16;
typedef __bf16 bf16x8 __attribute__((ext_vector_type(8)));
typedef float f32x4 __attribute__((ext_vector_type(4)));
typedef float f32x16 __attribute__((ext_vector_type(16)));

__device__ __forceinline__ u16 f2b(float f) {
  union { float f; unsigned u; } v; v.f = f;
  unsigned r = v.u + 0x7fffu + ((v.u >> 16) & 1u);
  return (u16)(r >> 16);
}
__device__ __forceinline__ float b2f(u16 b) {
  union { unsigned u; float f; } v; v.u = ((unsigned)b) << 16;
  return v.f;
}

// ---------------------------------------------------------------- cast fp32 -> bf16
__global__ __launch_bounds__(256) void cast_bf16(const float* __restrict__ in,
                                                 u16* __restrict__ out, int n4) {
  int i = blockIdx.x * 256 + threadIdx.x;
  if (i >= n4) return;
  float4 f = ((const float4*)in)[i];
  ushort4 r = make_ushort4(f2b(f.x), f2b(f.y), f2b(f.z), f2b(f.w));
  ((ushort4*)out)[i] = r;
}

// ---------------------------------------------------------------- fold fm weight into projection
// out[h*128+j, i] = sum_d fmw[j,d] * W[h*128+d, i]   (bf16 out)
__global__ __launch_bounds__(256) void fold_w(const float* __restrict__ W,
                                              const float* __restrict__ fmw,
                                              u16* __restrict__ out) {
  int hj = blockIdx.x;
  int h = hj >> 7, j = hj & 127;
  int i0 = threadIdx.x * 4;
  float a0 = 0.f, a1 = 0.f, a2 = 0.f, a3 = 0.f;
  const float* Wh = W + (size_t)(h * 128) * 1024 + i0;
  const float* fw = fmw + j * 128;
  for (int d = 0; d < 128; ++d) {
    float wv = fw[d];
    const float* wr = Wh + (size_t)d * 1024;
    a0 += wv * wr[0]; a1 += wv * wr[1]; a2 += wv * wr[2]; a3 += wv * wr[3];
  }
  ushort4 r = make_ushort4(f2b(a0), f2b(a1), f2b(a2), f2b(a3));
  ((ushort4*)(out + (size_t)hj * 1024))[threadIdx.x] = r;
}

// ---------------------------------------------------------------- m97-style BT GEMM
// C[M,N] = A[M,K] @ B[N,K]^T, A/B bf16, OUT_BF16 ? bf16 : fp32 output.
// SWZ=0: m-tiles sliced across XCDs (LNT = log2 n-tiles). SWZ=1: n-tiles sliced
// (for the vT GEMM, m-tiles == 8).
template <int OUT_BF16>
__global__ __launch_bounds__(256) void gemm_bt(const u16* __restrict__ A,
                                               const u16* __restrict__ B,
                                               void* __restrict__ Cv,
                                               int M, int N, int K, int SWZ, int LNT) {
  __shared__ u16 smem[16384];  // As[128*64] | Bs[128*64]; reused as C tile
  u16* As = smem;
  u16* Bs = smem + 8192;
  const int tid = threadIdx.x;
  int g = blockIdx.y * gridDim.x + blockIdx.x;
  int xcd = g & 7, local = g >> 3;
  int mt, nt;
  if (SWZ == 0) {
    mt = xcd * ((int)gridDim.y >> 3) + (local >> LNT);
    nt = local & ((1 << LNT) - 1);
  } else {
    nt = xcd * ((int)gridDim.x >> 3) + (local >> 3);
    mt = local & 7;
  }
  const int m0 = mt * 128, n0 = nt * 128;
  const int wave = tid >> 6, lane = tid & 63;
  const int wm = (wave >> 1) << 6, wn = (wave & 1) << 6;
  f32x4 acc[4][4] = {};
  const int srow = tid >> 3;         // 0..31
  const int scol = (tid & 7) << 3;   // 0..56
  const u16* Ab = A + (size_t)(m0 + srow) * K + scol;
  const u16* Bb = B + (size_t)(n0 + srow) * K + scol;
  u16* Asp = As + srow * 64 + scol;
  u16* Bsp = Bs + srow * 64 + scol;
  const int fm = lane & 15;
  const int fk = (lane >> 4) << 3;
  for (int kt = 0; kt < K; kt += 64) {
#pragma unroll
    for (int i = 0; i < 4; ++i) {
      __builtin_amdgcn_global_load_lds(
          (__attribute__((address_space(1))) unsigned int*)(Ab + (size_t)i * 32 * K + kt),
          (__attribute__((address_space(3))) unsigned int*)(Asp + i * 32 * 64), 16, 0, 0);
      __builtin_amdgcn_global_load_lds(
          (__attribute__((address_space(1))) unsigned int*)(Bb + (size_t)i * 32 * K + kt),
          (__attribute__((address_space(3))) unsigned int*)(Bsp + i * 32 * 64), 16, 0, 0);
    }
    __syncthreads();
#pragma unroll
    for (int kb = 0; kb < 2; ++kb) {
      bf16x8 af[4], bfr[4];
#pragma unroll
      for (int i = 0; i < 4; ++i)
        af[i] = *(const bf16x8*)(As + (wm + i * 16 + fm) * 64 + kb * 32 + fk);
#pragma unroll
      for (int j = 0; j < 4; ++j)
        bfr[j] = *(const bf16x8*)(Bs + (wn + j * 16 + fm) * 64 + kb * 32 + fk);
#pragma unroll
      for (int i = 0; i < 4; ++i)
#pragma unroll
        for (int j = 0; j < 4; ++j)
          acc[i][j] = __builtin_amdgcn_mfma_f32_16x16x32_bf16(af[i], bfr[j], acc[i][j], 0, 0, 0);
    }
    __syncthreads();
  }
  const int cr = (lane >> 4) << 2;
  const int cc = lane & 15;
  if (OUT_BF16) {
    u16* Cs = smem;  // 128x128 u16 = 32 KiB
#pragma unroll
    for (int i = 0; i < 4; ++i)
#pragma unroll
      for (int j = 0; j < 4; ++j)
#pragma unroll
        for (int r = 0; r < 4; ++r)
          Cs[(wm + i * 16 + cr + r) * 128 + wn + j * 16 + cc] = f2b(acc[i][j][r]);
    __syncthreads();
    u16* Cg = (u16*)Cv;
#pragma unroll
    for (int i = 0; i < 8; ++i) {
      int row = (i >> 1) * 32 + (tid >> 3);
      int col = ((i & 1) * 8 + (tid & 7)) * 8;
      *(uint4*)(Cg + (size_t)(m0 + row) * N + n0 + col) = *(const uint4*)(Cs + row * 128 + col);
    }
  } else {
    float* Csf = (float*)smem;  // 64x128 f32 = 32 KiB (two half-passes)
    float* Cg = (float*)Cv;
#pragma unroll
    for (int hh = 0; hh < 2; ++hh) {
      __syncthreads();
      if ((wm >> 6) == hh) {
#pragma unroll
        for (int i = 0; i < 4; ++i)
#pragma unroll
          for (int j = 0; j < 4; ++j)
#pragma unroll
            for (int r = 0; r < 4; ++r)
              Csf[(i * 16 + cr + r) * 128 + wn + j * 16 + cc] = acc[i][j][r];
      }
      __syncthreads();
#pragma unroll
      for (int i = 0; i < 8; ++i) {
        int row = (i >> 1) * 16 + (tid >> 4);
        int col = ((i & 1) * 16 + (tid & 15)) * 4;
        *(float4*)(Cg + (size_t)(m0 + hh * 64 + row) * N + n0 + col) =
            *(const float4*)(Csf + row * 128 + col);
      }
    }
  }
}

// ---------------------------------------------------------------- hedgehog softmax
// y: [T rows][2048] (merged q|k), rowhead rh -> row rh>>3, col (rh&7)*128+colbase.
// phi: [rh][256] bf16
__global__ __launch_bounds__(256) void hedgehog_sm(const u16* __restrict__ y,
                                                   const float* __restrict__ bias,
                                                   u16* __restrict__ phi, float scale,
                                                   int colbase) {
  int wave = threadIdx.x >> 6, lane = threadIdx.x & 63;
  int rh = blockIdx.x * 4 + wave;
  const u16* yr = y + (size_t)(rh >> 3) * 2048 + colbase + (rh & 7) * 128;
  float a1 = 2.f * (b2f(yr[lane]) + bias[lane]);
  float a2 = 2.f * (b2f(yr[lane + 64]) + bias[lane + 64]);
  float mx = fmaxf(fabsf(a1), fabsf(a2));
#pragma unroll
  for (int off = 32; off; off >>= 1) mx = fmaxf(mx, __shfl_xor(mx, off, 64));
  float e1 = __expf(a1 - mx), e2 = __expf(a2 - mx);
  float n1 = __expf(-a1 - mx), n2 = __expf(-a2 - mx);
  float s = e1 + e2 + n1 + n2;
#pragma unroll
  for (int off = 32; off; off >>= 1) s += __shfl_xor(s, off, 64);
  float inv = scale / s;
  u16* pr = phi + (size_t)rh * 256;
  pr[lane] = f2b(e1 * inv);
  pr[lane + 64] = f2b(e2 * inv);
  pr[lane + 128] = f2b(n1 * inv);
  pr[lane + 192] = f2b(n2 * inv);
}

// ---------------------------------------------------------------- attention phase A, C=128
// block g: chunk n = g&63 (128 timesteps), head h = g>>6.
// intra: scores=q@k^T (frags from global), mask, At(LDS bf16), o=At@vT (vT global).
// KV[vc][d] = vT x k^T with Kt staged in LDS halves (shares At region).
__global__ __launch_bounds__(256, 1) void attn_intra_kv2(const u16* __restrict__ phi_q,
                                                         const u16* __restrict__ phi_k,
                                                         const u16* __restrict__ vt,
                                                         float* __restrict__ o,
                                                         u16* __restrict__ kv) {
  __shared__ u16 lds[18432];  // At[128][136]=17408  U  Kt[256][72]=18432
  u16* At = lds;
  u16* Kt = lds;
  int g = blockIdx.x;
  int n = g & 63, h = g >> 6;
  int t0 = n * 128;
  const u16* qg = phi_q + ((size_t)t0 * 8 + h) * 256;  // row stride 2048
  const u16* kg = phi_k + ((size_t)t0 * 8 + h) * 256;
  const u16* vg = vt + (size_t)(h * 128) * 8192 + t0;  // vc rows, stride 8192
  int tid = threadIdx.x, lane = tid & 63, w = tid >> 6;
  const int fr = lane & 31, fg = (lane >> 5) << 3;
  const int rbase = (lane >> 5) << 2;
  const int mw = (w >> 1) << 6;  // t-half
  const int nw = (w & 1) << 6;   // t'-half (scores) / vc-half (o)

  // ---- scores
  f32x16 accS[2][2] = {};
#pragma unroll
  for (int ks = 0; ks < 16; ++ks) {
    bf16x8 a[2], b[2];
#pragma unroll
    for (int i = 0; i < 2; ++i)
      a[i] = *(const bf16x8*)(qg + (size_t)(mw + i * 32 + fr) * 2048 + ks * 16 + fg);
#pragma unroll
    for (int j = 0; j < 2; ++j)
      b[j] = *(const bf16x8*)(kg + (size_t)(nw + j * 32 + fr) * 2048 + ks * 16 + fg);
#pragma unroll
    for (int i = 0; i < 2; ++i)
#pragma unroll
      for (int j = 0; j < 2; ++j)
        accS[i][j] = __builtin_amdgcn_mfma_f32_32x32x16_bf16(a[i], b[j], accS[i][j], 0, 0, 0);
  }
  // ---- mask + At (causal incl diagonal)
#pragma unroll
  for (int i = 0; i < 2; ++i)
#pragma unroll
    for (int j = 0; j < 2; ++j) {
      int col = nw + j * 32 + (lane & 31);
#pragma unroll
      for (int r = 0; r < 16; ++r) {
        int row = mw + i * 32 + (r & 3) + ((r >> 2) << 3) + rbase;
        At[row * 136 + col] = f2b(col <= row ? accS[i][j][r] : 0.f);
      }
    }
  __syncthreads();
  // ---- o = At @ vT   (A = At rows t, B = vT rows vc)
  f32x16 accO[2][2] = {};
#pragma unroll
  for (int ks = 0; ks < 8; ++ks) {
    bf16x8 a[2], b[2];
#pragma unroll
    for (int i = 0; i < 2; ++i)
      a[i] = *(const bf16x8*)(At + (mw + i * 32 + fr) * 136 + ks * 16 + fg);
#pragma unroll
    for (int j = 0; j < 2; ++j)
      b[j] = *(const bf16x8*)(vg + (size_t)(nw + j * 32 + fr) * 8192 + ks * 16 + fg);
#pragma unroll
    for (int i = 0; i < 2; ++i)
#pragma unroll
      for (int j = 0; j < 2; ++j)
        accO[i][j] = __builtin_amdgcn_mfma_f32_32x32x16_bf16(a[i], b[j], accO[i][j], 0, 0, 0);
  }
  {
    float* og = o + ((size_t)t0 * 8 + h) * 128;  // row stride 1024
#pragma unroll
    for (int i = 0; i < 2; ++i)
#pragma unroll
      for (int j = 0; j < 2; ++j) {
        int vc = nw + j * 32 + (lane & 31);
#pragma unroll
        for (int r = 0; r < 16; ++r) {
          int row = mw + i * 32 + (r & 3) + ((r >> 2) << 3) + rbase;
          og[(size_t)row * 1024 + vc] = accO[i][j][r];
        }
      }
  }
  __syncthreads();  // At dead; Kt region reuse

  // ---- KV[vc][d] = sum_t' vT[vc][t'] k[t'][d]; wave w owns d in [w*64, w*64+64)
  const int nd = w << 6;
  f32x16 accKV[4][2] = {};
#pragma unroll
  for (int hb = 0; hb < 2; ++hb) {
    {  // stage Kt half: Kt[d 0..255][t'local 0..63] stride 72
      int r4 = (tid & 15) << 2;
      int d0 = (tid >> 4) << 4;
      u16 tmp[4][16];
#pragma unroll
      for (int r = 0; r < 4; ++r) {
        const u16* src = kg + (size_t)(hb * 64 + r4 + r) * 2048 + d0;
        *(uint4*)(tmp[r]) = *(const uint4*)src;
        *(uint4*)(tmp[r] + 8) = *(const uint4*)(src + 8);
      }
#pragma unroll
      for (int jj = 0; jj < 16; ++jj) {
        ushort4 pk = make_ushort4(tmp[0][jj], tmp[1][jj], tmp[2][jj], tmp[3][jj]);
        *(ushort4*)(Kt + (d0 + jj) * 72 + r4) = pk;
      }
    }
    __syncthreads();
#pragma unroll
    for (int ks = 0; ks < 4; ++ks) {
      bf16x8 a[4], b[2];
#pragma unroll
      for (int mi = 0; mi < 4; ++mi)
        a[mi] = *(const bf16x8*)(vg + (size_t)(mi * 32 + fr) * 8192 + hb * 64 + ks * 16 + fg);
#pragma unroll
      for (int nj = 0; nj < 2; ++nj)
        b[nj] = *(const bf16x8*)(Kt + (nd + nj * 32 + fr) * 72 + ks * 16 + fg);
#pragma unroll
      for (int mi = 0; mi < 4; ++mi)
#pragma unroll
        for (int nj = 0; nj < 2; ++nj)
          accKV[mi][nj] =
              __builtin_amdgcn_mfma_f32_32x32x16_bf16(a[mi], b[nj], accKV[mi][nj], 0, 0, 0);
    }
    __syncthreads();
  }
  {
    u16* kvg = kv + (size_t)g * 32768;
#pragma unroll
    for (int mi = 0; mi < 4; ++mi)
#pragma unroll
      for (int nj = 0; nj < 2; ++nj) {
        f32x16 acc = accKV[mi][nj];
        int d = nd + nj * 32 + (lane & 31);
#pragma unroll
        for (int r = 0; r < 16; ++r) {
          int vc = mi * 32 + (r & 3) + ((r >> 2) << 3) + rbase;
          kvg[(size_t)vc * 256 + d] = f2b(acc[r]);
        }
      }
  }
}

// ---------------------------------------------------------------- attention phase B
// in-place exclusive prefix over 64 chunk-KVs per h; 4 bf16 per thread, fp32 carry
__global__ __launch_bounds__(256) void kv_scan2(u16* __restrict__ kv) {
  int idx = blockIdx.x * 256 + threadIdx.x;  // 0..65535
  int h = idx >> 13;                         // 8192 lanes per h
  int e4 = idx & 8191;
  u16* p = kv + (size_t)h * 2097152 + (size_t)e4 * 4;
  float run[4] = {};
  for (int nn = 0; nn < 64; ++nn) {
    uint2 raw = *(const uint2*)p;
    u16* rv = (u16*)&raw;
    uint2 outw;
    u16* ov = (u16*)&outw;
#pragma unroll
    for (int i = 0; i < 4; ++i) {
      float v = b2f(rv[i]);
      ov[i] = f2b(run[i]);
      run[i] += v;
    }
    *(uint2*)p = outw;
    p += 32768;
  }
}

// ---------------------------------------------------------------- attention phase C, C=128
// o += q @ S  (S = exclusive prefix KV, [vc][d] global); zero LDS
__global__ __launch_bounds__(256, 1) void attn_inter2(const u16* __restrict__ phi_q,
                                                      const u16* __restrict__ kv,
                                                      float* __restrict__ o) {
  int g = blockIdx.x;
  int n = g & 63, h = g >> 6;
  int t0 = n * 128;
  const u16* qg = phi_q + ((size_t)t0 * 8 + h) * 256;
  const u16* sg = kv + (size_t)g * 32768;
  int tid = threadIdx.x, lane = tid & 63, w = tid >> 6;
  const int fr = lane & 31, fg = (lane >> 5) << 3;
  const int rbase = (lane >> 5) << 2;
  const int mw = (w >> 1) << 6;  // t-half
  const int nw = (w & 1) << 6;   // vc-half
  f32x16 acc[2][2] = {};
#pragma unroll
  for (int ks = 0; ks < 16; ++ks) {
    bf16x8 a[2], b[2];
#pragma unroll
    for (int i = 0; i < 2; ++i)
      a[i] = *(const bf16x8*)(qg + (size_t)(mw + i * 32 + fr) * 2048 + ks * 16 + fg);
#pragma unroll
    for (int j = 0; j < 2; ++j)
      b[j] = *(const bf16x8*)(sg + (size_t)(nw + j * 32 + fr) * 256 + ks * 16 + fg);
#pragma unroll
    for (int i = 0; i < 2; ++i)
#pragma unroll
      for (int j = 0; j < 2; ++j)
        acc[i][j] = __builtin_amdgcn_mfma_f32_32x32x16_bf16(a[i], b[j], acc[i][j], 0, 0, 0);
  }
  float* og = o + ((size_t)t0 * 8 + h) * 128;
#pragma unroll
  for (int i = 0; i < 2; ++i)
#pragma unroll
    for (int j = 0; j < 2; ++j) {
      int vc = nw + j * 32 + (lane & 31);
#pragma unroll
      for (int r = 0; r < 16; ++r) {
        int row = mw + i * 32 + (r & 3) + ((r >> 2) << 3) + rbase;
        og[(size_t)row * 1024 + vc] += acc[i][j][r];
      }
    }
}

// ---------------------------------------------------------------- rmsnorm (per 1024-dim row)
__global__ __launch_bounds__(256) void rmsnorm_k(const float* __restrict__ o,
                                                 u16* __restrict__ on) {
  __shared__ float red[4];
  int row = blockIdx.x;
  const float* orow = o + (size_t)row * 1024;
  int tid = threadIdx.x;
  float4 v = ((const float4*)orow)[tid];
  float ss = v.x * v.x + v.y * v.y + v.z * v.z + v.w * v.w;
#pragma unroll
  for (int off = 32; off; off >>= 1) ss += __shfl_xor(ss, off, 64);
  if ((tid & 63) == 0) red[tid >> 6] = ss;
  __syncthreads();
  float tot = red[0] + red[1] + red[2] + red[3];
  float rms = rsqrtf(tot * (1.f / 1024.f) + 1e-5f);
  ushort4 r = make_ushort4(f2b(v.x * rms), f2b(v.y * rms), f2b(v.z * rms), f2b(v.w * rms));
  ((ushort4*)(on + (size_t)row * 1024))[tid] = r;
}

// ---------------------------------------------------------------- launch
extern "C" void kernel_launch(void* const* d_in, const int* in_sizes, int n_in,
                              void* d_out, int out_size, void* d_ws, size_t ws_size,
                              hipStream_t stream) {
  const float* x     = (const float*)d_in[0];
  const float* Wq    = (const float*)d_in[1];
  const float* Wk    = (const float*)d_in[2];
  const float* Wv    = (const float*)d_in[3];
  const float* Wo    = (const float*)d_in[4];
  const float* fmq_w = (const float*)d_in[5];
  const float* fmq_b = (const float*)d_in[6];
  const float* fmk_w = (const float*)d_in[7];
  const float* fmk_b = (const float*)d_in[8];

  // Per-batch workspace (sequential batches; 184 MiB total, proven safe in r3/r4).
  // Aliasing: kvb[0,33.5 MiB) overlaps xb[0,16) + yb head [16,33.5) — both dead
  // before attn_intra_kv2 writes kv; onb[48,64) disjoint from kv.
  char* ws = (char*)d_ws;
  u16*   kvb  = (u16*)(ws + 0);            // 33.5 MiB (64 chunks x 8 h x 64 KiB)
  u16*   xb   = (u16*)(ws + 0);            // 16 MiB
  u16*   yb   = (u16*)(ws + 16777216);     // 32 MiB (merged q|k, [8192][2048])
  u16*   onb  = (u16*)(ws + 50331648);     // 16 MiB
  u16*   phiq = (u16*)(ws + 67108864);     // 32 MiB
  u16*   phik = (u16*)(ws + 100663296);    // 32 MiB
  u16*   vtb  = (u16*)(ws + 134217728);    // 16 MiB ([1024 vc-rows][8192 t])
  float* obuf = (float*)(ws + 150994944);  // 32 MiB
  u16*   wqkc = (u16*)(ws + 184549376);    // 4 MiB ([2048][1024]: q rows | k rows)
  u16*   wvb  = (u16*)(ws + 188743680);    // 2 MiB
  u16*   wob  = (u16*)(ws + 190840832);    // 2 MiB -> end 192937984 (184 MiB)

  // weight prep (once)
  cast_bf16<<<1024, 256, 0, stream>>>(Wv, wvb, 262144);
  cast_bf16<<<1024, 256, 0, stream>>>(Wo, wob, 262144);
  fold_w<<<1024, 256, 0, stream>>>(Wq, fmq_w, wqkc);
  fold_w<<<1024, 256, 0, stream>>>(Wk, fmk_w, wqkc + 1048576);

  for (int b = 0; b < 2; ++b) {
    const float* xsrc = x + (size_t)b * 8388608;
    float* osrc = (float*)d_out + (size_t)b * 8388608;
    cast_bf16<<<8192, 256, 0, stream>>>(xsrc, xb, 2097152);
    // merged q|k projection: [8192][2048]
    gemm_bt<1><<<dim3(16, 64), 256, 0, stream>>>(xb, wqkc, yb, 8192, 2048, 1024, 0, 4);
    hedgehog_sm<<<16384, 256, 0, stream>>>(yb, fmq_b, phiq, 0.0625f, 0);     // 256^-0.5
    hedgehog_sm<<<16384, 256, 0, stream>>>(yb, fmk_b, phik, 1.0f, 1024);
    // v^T via operand swap: C[1024][8192] = Wv @ x^T
    gemm_bt<1><<<dim3(64, 8), 256, 0, stream>>>(wvb, xb, vtb, 1024, 8192, 1024, 1, 0);
    // attention, C=128
    attn_intra_kv2<<<512, 256, 0, stream>>>(phiq, phik, vtb, obuf, kvb);
    kv_scan2<<<256, 256, 0, stream>>>(kvb);
    attn_inter2<<<512, 256, 0, stream>>>(phiq, kvb, obuf);
    // rmsnorm + output projection
    rmsnorm_k<<<8192, 256, 0, stream>>>(obuf, onb);
    gemm_bt<0><<<dim3(8, 64), 256, 0, stream>>>(onb, wob, osrc, 8192, 1024, 1024, 0, 3);
  }
}